// Round 1
// baseline (399.710 us; speedup 1.0000x reference)
//
#include <hip/hip_runtime.h>
#include <math.h>

#define WIN 11
#define PAD 5
#define TILE 32
#define REG (TILE + WIN - 1)   // 42
#define RSTRIDE (REG + 2)      // 44, padded LDS row stride

struct GW { float g[WIN]; };

// Fused separable SSIM per level: stage tile+halo in LDS, horizontal pass for
// 5 moment maps, vertical pass + SSIM formula, block reduce -> atomicAdd.
__global__ __launch_bounds__(256) void ssim_kernel(
    const float* __restrict__ i1, const float* __restrict__ i2,
    int H, int W, double* __restrict__ acc, GW gw)
{
    __shared__ float s1[REG][RSTRIDE];
    __shared__ float s2[REG][RSTRIDE];
    __shared__ float h[5][REG][TILE];
    __shared__ float wsum[4];

    const int tid = threadIdx.x;
    const int img = blockIdx.y;                 // 0..47 (b*3+c)
    const int tiles_x = W / TILE;
    const int tx = blockIdx.x % tiles_x;
    const int ty = blockIdx.x / tiles_x;
    const int x0 = tx * TILE - PAD;
    const int y0 = ty * TILE - PAD;
    const float* p1 = i1 + (size_t)img * H * W;
    const float* p2 = i2 + (size_t)img * H * W;

    // ---- stage tile + halo (zero padding outside image) ----
    for (int i = tid; i < REG * REG; i += 256) {
        int r = i / REG, c = i % REG;
        int y = y0 + r, x = x0 + c;
        float a = 0.f, b = 0.f;
        if (y >= 0 && y < H && x >= 0 && x < W) {
            size_t o = (size_t)y * W + x;
            a = p1[o];
            b = p2[o];
        }
        s1[r][c] = a;
        s2[r][c] = b;
    }
    __syncthreads();

    // ---- horizontal pass: 5 moment rows over the 42-row region ----
    for (int i = tid; i < REG * TILE; i += 256) {
        int r = i / TILE, c = i % TILE;
        float h1 = 0.f, h2 = 0.f, h11 = 0.f, h22 = 0.f, h12 = 0.f;
#pragma unroll
        for (int dx = 0; dx < WIN; ++dx) {
            float g = gw.g[dx];
            float a = s1[r][c + dx];
            float b = s2[r][c + dx];
            float ga = g * a;
            float gb = g * b;
            h1  = fmaf(g,  a, h1);
            h2  = fmaf(g,  b, h2);
            h11 = fmaf(ga, a, h11);
            h22 = fmaf(gb, b, h22);
            h12 = fmaf(ga, b, h12);
        }
        h[0][r][c] = h1;
        h[1][r][c] = h2;
        h[2][r][c] = h11;
        h[3][r][c] = h22;
        h[4][r][c] = h12;
    }
    __syncthreads();

    // ---- vertical pass + SSIM ----
    const float C1v = 1e-4f;   // 0.01^2
    const float C2v = 9e-4f;   // 0.03^2
    float part = 0.f;
    for (int i = tid; i < TILE * TILE; i += 256) {
        int r = i / TILE, c = i % TILE;
        float v1 = 0.f, v2 = 0.f, v11 = 0.f, v22 = 0.f, v12 = 0.f;
#pragma unroll
        for (int dy = 0; dy < WIN; ++dy) {
            float g = gw.g[dy];
            v1  = fmaf(g, h[0][r + dy][c], v1);
            v2  = fmaf(g, h[1][r + dy][c], v2);
            v11 = fmaf(g, h[2][r + dy][c], v11);
            v22 = fmaf(g, h[3][r + dy][c], v22);
            v12 = fmaf(g, h[4][r + dy][c], v12);
        }
        float m1sq = v1 * v1;
        float m2sq = v2 * v2;
        float m12  = v1 * v2;
        float sg1  = v11 - m1sq;
        float sg2  = v22 - m2sq;
        float sg12 = v12 - m12;
        float num = (2.f * m12 + C1v) * (2.f * sg12 + C2v);
        float den = (m1sq + m2sq + C1v) * (sg1 + sg2 + C2v);
        part += num / den;
    }

    // ---- block reduction (wave64 shuffle + LDS across 4 waves) ----
#pragma unroll
    for (int off = 32; off > 0; off >>= 1)
        part += __shfl_down(part, off, 64);
    int lane = tid & 63, wv = tid >> 6;
    if (lane == 0) wsum[wv] = part;
    __syncthreads();
    if (tid == 0) {
        float s = wsum[0] + wsum[1] + wsum[2] + wsum[3];
        atomicAdd(acc, (double)s);
    }
}

// 2x2 avg-pool for both images at once. Ho,Wo are OUTPUT dims; total = 48*Ho*Wo.
__global__ __launch_bounds__(256) void pool2_kernel(
    const float* __restrict__ in1, const float* __restrict__ in2,
    float* __restrict__ out1, float* __restrict__ out2,
    int Ho, int Wo, int total)
{
    int idx = blockIdx.x * blockDim.x + threadIdx.x;
    if (idx >= total) return;
    int x = idx % Wo;
    int rest = idx / Wo;
    int y = rest % Ho;
    int img = rest / Ho;
    int Wi = Wo * 2;
    size_t base = ((size_t)img * (Ho * 2) + (size_t)y * 2) * Wi + (size_t)x * 2;
    float a = (in1[base] + in1[base + 1] + in1[base + Wi] + in1[base + Wi + 1]) * 0.25f;
    float b = (in2[base] + in2[base + 1] + in2[base + Wi] + in2[base + Wi + 1]) * 0.25f;
    out1[idx] = a;
    out2[idx] = b;
}

__global__ void init_kernel(double* acc)
{
    if (threadIdx.x < 5) acc[threadIdx.x] = 0.0;
}

__global__ void final_kernel(const double* __restrict__ acc, float* __restrict__ out)
{
    double loss = 0.0;
#pragma unroll
    for (int l = 0; l < 5; ++l) {
        double cnt = 48.0 * (double)(512 >> l) * (double)(512 >> l);
        loss += 1.0 - acc[l] / cnt;
    }
    out[0] = (float)loss;
}

extern "C" void kernel_launch(void* const* d_in, const int* in_sizes, int n_in,
                              void* d_out, int out_size, void* d_ws, size_t ws_size,
                              hipStream_t stream)
{
    const float* img1 = (const float*)d_in[0];
    const float* img2 = (const float*)d_in[1];
    float* out = (float*)d_out;

    // 1D gaussian (sigma=1.5, k=11), matches reference construction
    GW gw;
    double gs[WIN], sum = 0.0;
    for (int i = 0; i < WIN; ++i) {
        double ax = (double)i - 5.0;
        gs[i] = exp(-(ax * ax) / 4.5);
        sum += gs[i];
    }
    for (int i = 0; i < WIN; ++i) gw.g[i] = (float)(gs[i] / sum);

    // workspace layout: 64B header (5 doubles acc), then pyramid images
    double* acc = (double*)d_ws;
    float* base = (float*)((char*)d_ws + 64);
    const size_t n1 = 48ull * 256 * 256;
    const size_t n2 = 48ull * 128 * 128;
    const size_t n3 = 48ull * 64 * 64;
    const size_t n4 = 48ull * 32 * 32;
    float* a1 = base;      float* b1 = a1 + n1;
    float* a2 = b1 + n1;   float* b2 = a2 + n2;
    float* a3 = b2 + n2;   float* b3 = a3 + n3;
    float* a4 = b3 + n3;   float* b4 = a4 + n4;

    hipLaunchKernelGGL(init_kernel, dim3(1), dim3(64), 0, stream, acc);

    // build pyramid
    hipLaunchKernelGGL(pool2_kernel, dim3((unsigned)((n1 + 255) / 256)), dim3(256), 0, stream,
                       img1, img2, a1, b1, 256, 256, (int)n1);
    hipLaunchKernelGGL(pool2_kernel, dim3((unsigned)((n2 + 255) / 256)), dim3(256), 0, stream,
                       a1, b1, a2, b2, 128, 128, (int)n2);
    hipLaunchKernelGGL(pool2_kernel, dim3((unsigned)((n3 + 255) / 256)), dim3(256), 0, stream,
                       a2, b2, a3, b3, 64, 64, (int)n3);
    hipLaunchKernelGGL(pool2_kernel, dim3((unsigned)((n4 + 255) / 256)), dim3(256), 0, stream,
                       a3, b3, a4, b4, 32, 32, (int)n4);

    // fused SSIM per level
    hipLaunchKernelGGL(ssim_kernel, dim3(16 * 16, 48), dim3(256), 0, stream,
                       img1, img2, 512, 512, acc + 0, gw);
    hipLaunchKernelGGL(ssim_kernel, dim3(8 * 8, 48), dim3(256), 0, stream,
                       a1, b1, 256, 256, acc + 1, gw);
    hipLaunchKernelGGL(ssim_kernel, dim3(4 * 4, 48), dim3(256), 0, stream,
                       a2, b2, 128, 128, acc + 2, gw);
    hipLaunchKernelGGL(ssim_kernel, dim3(2 * 2, 48), dim3(256), 0, stream,
                       a3, b3, 64, 64, acc + 3, gw);
    hipLaunchKernelGGL(ssim_kernel, dim3(1, 48), dim3(256), 0, stream,
                       a4, b4, 32, 32, acc + 4, gw);

    hipLaunchKernelGGL(final_kernel, dim3(1), dim3(1), 0, stream, acc, out);
}

// Round 2
// 363.287 us; speedup vs baseline: 1.1003x; 1.1003x over previous
//
#include <hip/hip_runtime.h>
#include <math.h>

#define WIN 11
#define PAD 5
#define TILE 32
#define REG 42            // TILE + WIN - 1
#define RS2 43            // pq row stride in float2 units (43*8 B rows)
#define HSTR 44           // h row stride in floats; 44*4=176 B, 16B-aligned

struct GW { float g[WIN]; };

// ---------------------------------------------------------------------------
// Fused all-level SSIM. Grid: (341, 48). blockIdx.x ranges decode the level:
// L0:256 tiles, L1:64, L2:16, L3:4, L4:1 (32x32 output tile each).
// p=a+b, q=a-b -> only 4 conv maps needed (Mp,Mq,Sp,Sq).
// ---------------------------------------------------------------------------
__global__ __launch_bounds__(256, 4) void ssim_all_kernel(
    const float* __restrict__ i1_0, const float* __restrict__ i2_0,
    const float* __restrict__ a1, const float* __restrict__ b1,
    const float* __restrict__ a2, const float* __restrict__ b2,
    const float* __restrict__ a3, const float* __restrict__ b3,
    const float* __restrict__ a4, const float* __restrict__ b4,
    double* __restrict__ acc, GW gw)
{
    __shared__ float2 pq[REG * RS2];                   // 14448 B
    __shared__ __align__(16) float h[4][TILE][HSTR];   // 22528 B
    __shared__ float wsum[4];

    const int tid = threadIdx.x;

    // ---- level decode (wave-uniform) ----
    int bx = blockIdx.x;
    int lvl, tbase;
    if (bx < 256)      { lvl = 0; tbase = 0; }
    else if (bx < 320) { lvl = 1; tbase = 256; }
    else if (bx < 336) { lvl = 2; tbase = 320; }
    else if (bx < 340) { lvl = 3; tbase = 336; }
    else               { lvl = 4; tbase = 340; }
    const int t = bx - tbase;
    const int W = 512 >> lvl;            // square images
    const int tiles_x = W >> 5;
    const float* p1; const float* p2;
    switch (lvl) {
      case 0:  p1 = i1_0; p2 = i2_0; break;
      case 1:  p1 = a1;   p2 = b1;   break;
      case 2:  p1 = a2;   p2 = b2;   break;
      case 3:  p1 = a3;   p2 = b3;   break;
      default: p1 = a4;   p2 = b4;   break;
    }
    const size_t imgoff = (size_t)blockIdx.y * W * W;
    p1 += imgoff; p2 += imgoff;

    const int tx = t % tiles_x, ty = t / tiles_x;
    const int x0 = tx * TILE - PAD;
    const int y0 = ty * TILE - PAD;

    // ---- stage: load halo region, store (p,q) interleaved ----
    for (int i = tid; i < REG * REG; i += 256) {
        int r = i / REG, c = i - r * REG;
        int y = y0 + r, x = x0 + c;
        float a = 0.f, b = 0.f;
        if ((unsigned)y < (unsigned)W && (unsigned)x < (unsigned)W) {
            size_t o = (size_t)y * W + x;
            a = p1[o];
            b = p2[o];
        }
        pq[r * RS2 + c] = make_float2(a + b, a - b);
    }
    __syncthreads();

    // ---- horizontal pass: 4 moment maps, transposed store for b128 V-reads ----
    for (int i = tid; i < REG * TILE; i += 256) {
        int r = i >> 5, c = i & 31;
        const float2* row = &pq[r * RS2 + c];
        float mp = 0.f, mq = 0.f, sp = 0.f, sq = 0.f;
#pragma unroll
        for (int dx = 0; dx < WIN; ++dx) {
            float g = gw.g[dx];
            float2 v = row[dx];
            float gp = g * v.x, gq = g * v.y;
            mp += gp; mq += gq;
            sp = fmaf(gp, v.x, sp);
            sq = fmaf(gq, v.y, sq);
        }
        h[0][c][r] = mp;
        h[1][c][r] = mq;
        h[2][c][r] = sp;
        h[3][c][r] = sq;
    }
    __syncthreads();

    // ---- vertical pass, 4 output rows per thread via float4 column loads ----
    const float C1v = 1e-4f;
    const float C2v = 9e-4f;
    float part = 0.f;
    {
        int xc = tid & 31;
        int r0 = (tid >> 5) << 2;          // 0,4,...,28
        float d[4][4];                      // [map][k]
#pragma unroll
        for (int m = 0; m < 4; ++m) {
            const float4* col = (const float4*)&h[m][xc][r0];
            float4 v0 = col[0], v1 = col[1], v2 = col[2], v3 = col[3];
            float vv[16] = { v0.x, v0.y, v0.z, v0.w,
                             v1.x, v1.y, v1.z, v1.w,
                             v2.x, v2.y, v2.z, v2.w,
                             v3.x, v3.y, v3.z, v3.w };
#pragma unroll
            for (int k = 0; k < 4; ++k) {
                float s = 0.f;
#pragma unroll
                for (int dy = 0; dy < WIN; ++dy)
                    s = fmaf(gw.g[dy], vv[k + dy], s);
                d[m][k] = s;
            }
        }
#pragma unroll
        for (int k = 0; k < 4; ++k) {
            float A   = d[0][k] * d[0][k];      // Mp^2
            float B   = d[1][k] * d[1][k];      // Mq^2
            float ABp = A + B, ABm = A - B;
            float SSp = d[2][k] + d[3][k];
            float SSm = d[2][k] - d[3][k];
            float n1 = fmaf(0.5f, ABm, C1v);          // 2*m12 + C1
            float n2 = fmaf(0.5f, SSm - ABm, C2v);    // 2*s12 + C2
            float e1 = fmaf(0.5f, ABp, C1v);          // m1^2+m2^2 + C1
            float e2 = fmaf(0.5f, SSp - ABp, C2v);    // s1+s2 + C2
            part += (n1 * n2) * __builtin_amdgcn_rcpf(e1 * e2);
        }
    }

    // ---- block reduction ----
#pragma unroll
    for (int off = 32; off > 0; off >>= 1)
        part += __shfl_down(part, off, 64);
    int lane = tid & 63, wv = tid >> 6;
    if (lane == 0) wsum[wv] = part;
    __syncthreads();
    if (tid == 0) {
        float s = wsum[0] + wsum[1] + wsum[2] + wsum[3];
        atomicAdd(acc + lvl, (double)s);
    }
}

// ---------------------------------------------------------------------------
// One-shot pyramid: each block pools a 64x64 region of one image down to
// L1..L4 (reads L0 once). Grid: (64, 96); y = image index (0..47 img1,
// 48..95 img2). Block (0,0) also zeroes the 5 accumulators.
// ---------------------------------------------------------------------------
__global__ __launch_bounds__(256) void pool_all_kernel(
    const float* __restrict__ i1, const float* __restrict__ i2,
    float* __restrict__ a1, float* __restrict__ b1,
    float* __restrict__ a2, float* __restrict__ b2,
    float* __restrict__ a3, float* __restrict__ b3,
    float* __restrict__ a4, float* __restrict__ b4,
    double* __restrict__ acc)
{
    __shared__ float l1[32][33];
    __shared__ float l2[16][17];
    __shared__ float l3[8][9];
    const int tid = threadIdx.x;
    const int im = blockIdx.y;
    const int t = blockIdx.x;
    const int tx = t & 7, ty = t >> 3;
    const bool second = im >= 48;
    const int ii = second ? im - 48 : im;
    const float* src = (second ? i2 : i1) + (size_t)ii * 512 * 512;
    float* o1 = (second ? b1 : a1) + (size_t)ii * 256 * 256;
    float* o2 = (second ? b2 : a2) + (size_t)ii * 128 * 128;
    float* o3 = (second ? b3 : a3) + (size_t)ii * 64 * 64;
    float* o4 = (second ? b4 : a4) + (size_t)ii * 32 * 32;
    const int X0 = tx * 64, Y0 = ty * 64;

    if (blockIdx.x == 0 && blockIdx.y == 0 && tid < 5)
        acc[tid] = 0.0;

    // L1: 32x32 outputs per block, 4 per thread (float2 row-pair loads)
#pragma unroll
    for (int k = 0; k < 4; ++k) {
        int idx = tid + k * 256;
        int xo = idx & 31, yo = idx >> 5;
        const float* rp = src + (size_t)(Y0 + 2 * yo) * 512 + (X0 + 2 * xo);
        float2 r0 = *(const float2*)rp;
        float2 r1 = *(const float2*)(rp + 512);
        float v = (r0.x + r0.y + r1.x + r1.y) * 0.25f;
        l1[yo][xo] = v;
        o1[(size_t)((Y0 >> 1) + yo) * 256 + ((X0 >> 1) + xo)] = v;
    }
    __syncthreads();

    // L2: 16x16
    {
        int xo = tid & 15, yo = tid >> 4;
        float v = (l1[2*yo][2*xo] + l1[2*yo][2*xo+1] +
                   l1[2*yo+1][2*xo] + l1[2*yo+1][2*xo+1]) * 0.25f;
        l2[yo][xo] = v;
        o2[(size_t)((Y0 >> 2) + yo) * 128 + ((X0 >> 2) + xo)] = v;
    }
    __syncthreads();

    // L3: 8x8
    if (tid < 64) {
        int xo = tid & 7, yo = tid >> 3;
        float v = (l2[2*yo][2*xo] + l2[2*yo][2*xo+1] +
                   l2[2*yo+1][2*xo] + l2[2*yo+1][2*xo+1]) * 0.25f;
        l3[yo][xo] = v;
        o3[(size_t)((Y0 >> 3) + yo) * 64 + ((X0 >> 3) + xo)] = v;
    }
    __syncthreads();

    // L4: 4x4
    if (tid < 16) {
        int xo = tid & 3, yo = tid >> 2;
        float v = (l3[2*yo][2*xo] + l3[2*yo][2*xo+1] +
                   l3[2*yo+1][2*xo] + l3[2*yo+1][2*xo+1]) * 0.25f;
        o4[(size_t)((Y0 >> 4) + yo) * 32 + ((X0 >> 4) + xo)] = v;
    }
}

__global__ void final_kernel(const double* __restrict__ acc, float* __restrict__ out)
{
    double loss = 0.0;
#pragma unroll
    for (int l = 0; l < 5; ++l) {
        double cnt = 48.0 * (double)(512 >> l) * (double)(512 >> l);
        loss += 1.0 - acc[l] / cnt;
    }
    out[0] = (float)loss;
}

extern "C" void kernel_launch(void* const* d_in, const int* in_sizes, int n_in,
                              void* d_out, int out_size, void* d_ws, size_t ws_size,
                              hipStream_t stream)
{
    const float* img1 = (const float*)d_in[0];
    const float* img2 = (const float*)d_in[1];
    float* out = (float*)d_out;

    // 1D gaussian (sigma=1.5, k=11) to match reference construction
    GW gw;
    double gs[WIN], sum = 0.0;
    for (int i = 0; i < WIN; ++i) {
        double ax = (double)i - 5.0;
        gs[i] = exp(-(ax * ax) / 4.5);
        sum += gs[i];
    }
    for (int i = 0; i < WIN; ++i) gw.g[i] = (float)(gs[i] / sum);

    // workspace: 64B header (5 doubles), then pyramid
    double* acc = (double*)d_ws;
    float* base = (float*)((char*)d_ws + 64);
    const size_t n1 = 48ull * 256 * 256;
    const size_t n2 = 48ull * 128 * 128;
    const size_t n3 = 48ull * 64 * 64;
    const size_t n4 = 48ull * 32 * 32;
    float* a1 = base;      float* b1 = a1 + n1;
    float* a2 = b1 + n1;   float* b2 = a2 + n2;
    float* a3 = b2 + n2;   float* b3 = a3 + n3;
    float* a4 = b3 + n3;   float* b4 = a4 + n4;

    hipLaunchKernelGGL(pool_all_kernel, dim3(64, 96), dim3(256), 0, stream,
                       img1, img2, a1, b1, a2, b2, a3, b3, a4, b4, acc);

    hipLaunchKernelGGL(ssim_all_kernel, dim3(341, 48), dim3(256), 0, stream,
                       img1, img2, a1, b1, a2, b2, a3, b3, a4, b4, acc, gw);

    hipLaunchKernelGGL(final_kernel, dim3(1), dim3(1), 0, stream, acc, out);
}